// Round 19
// baseline (154.690 us; speedup 1.0000x reference)
//
#include <hip/hip_runtime.h>
#include <cfloat>
#include <math.h>

// Exact-replication KNN (k=10, +self) + rank-column gather max-pool.
// NUMERICS FROZEN (R3 pass, absmax 0.0): fp32 chains
//   sq  = fma(z,z, fma(y,y, rn(x*x)))
//   dot = fma(z,z', fma(y,y', rn(x*x')))
//   d   = fma(dot, -2, rn(sq_i+sq_j))    [== rn(sum - rn(2*dot)), 2*dot exact]
// Selection order = jax top_k = ascending lexicographic (d, orig_idx) —
// proven order-independent in R8/R9 (absmax 0.0, nondeterministic scatter).
//
// Round 29: aggregate-VALU reductions. R28 (WQ=1) hit 149.7 wall / 74 knn
// with VALUBusy ~68% — the kernel is now throughput-bound on total issued
// instructions, not the tail (ratio 1.7x). Two exact-preserving cuts:
//  - QCAP 96 -> 192: compactions (~420 inst of 32-step ballot radix each)
//    halve in count — after a compact W is the EXACT running 11th so
//    appends nearly stop; bigger queue frontloads more appends per radix.
//    Compact now reads 3 lane-regs (RADIX11_3). LDS 8 -> 11 KB (VGPR still
//    the occupancy binder).
//  - own-tile dedup: append from the saved init distances instead of
//    recomputing them.
// Scan path / gates / compaction semantics / final sort unchanged -> exact.
// Kept: R14 init radix, R16 ring, R22 lb gate, R25 queues, R26 no-pre-gate,
// R27/R28 WQ lever.

#define N_PTS    16384
#define C_FEAT   64
#define KK       11
#define NCELLS   4096                 // 16^3 Morton cells
#define TILE     128                  // sorted points per tile
#define NTILES   (N_PTS / TILE)       // 128
#define WQ       1
#define NWAVES   4
#define NTHREADS (NWAVES * 64)
#define QPB      (NWAVES * WQ)        // 4 queries per block
#define QCAP     192                  // queue slots per query

// d_ws layout (bytes)
#define WS_CAND  0                            // float4[2][N_PTS]   512 KB
#define WS_AABB  (WS_CAND + 2*N_PTS*16)       // float[2][NTILES][6]  6 KB
#define WS_HIST  (WS_AABB + 2*NTILES*6*4)     // int[2][NCELLS]      32 KB

__device__ __forceinline__ int cell_of(float x, float y, float z) {
    int cx = (int)floorf((x + 4.5f) * (16.0f / 9.0f));
    int cy = (int)floorf((y + 4.5f) * (16.0f / 9.0f));
    int cz = (int)floorf((z + 4.5f) * (16.0f / 9.0f));
    cx = min(15, max(0, cx));
    cy = min(15, max(0, cy));
    cz = min(15, max(0, cz));
    int m = 0;
    #pragma unroll
    for (int b = 0; b < 4; ++b)
        m |= (((cx >> b) & 1) << (3 * b)) |
             (((cy >> b) & 1) << (3 * b + 1)) |
             (((cz >> b) & 1) << (3 * b + 2));
    return m;
}

// Monotone (order-preserving, bijective) float<->uint key.
__device__ __forceinline__ unsigned keyf(float f) {
    const unsigned u = __float_as_uint(f);
    return (u & 0x80000000u) ? ~u : (u | 0x80000000u);
}
__device__ __forceinline__ float unkeyf(unsigned k) {
    return __uint_as_float((k & 0x80000000u) ? (k ^ 0x80000000u) : ~k);
}

// 128 blocks x 256 thr, one point per thread. Global atomics into hist
// (pre-zeroed by hipMemsetAsync).
__global__ __launch_bounds__(256) void hist_kernel(
    const float* __restrict__ src_c, const float* __restrict__ tgt_c,
    int* __restrict__ hist)
{
    const int inst = blockIdx.x >> 6;           // 64 blocks per instance
    const float* __restrict__ coords = inst ? tgt_c : src_c;
    int* __restrict__ h = hist + inst * NCELLS;
    const int p = ((blockIdx.x & 63) << 8) + threadIdx.x;
    const float* c = coords + (size_t)p * 3;
    atomicAdd(&h[cell_of(c[0], c[1], c[2])], 1);
}

// One block per instance. Barrier scan; leaves h[cell] = exclusive base.
__global__ __launch_bounds__(1024) void scan_kernel(int* __restrict__ hist)
{
    const int inst = blockIdx.x;
    int* __restrict__ h = hist + inst * NCELLS;
    __shared__ int sd[1024];
    const int t = threadIdx.x;

    int v[4], ssum = 0;
    #pragma unroll
    for (int j = 0; j < 4; ++j) { v[j] = h[t * 4 + j]; ssum += v[j]; }
    sd[t] = ssum;
    __syncthreads();
    for (int off = 1; off < 1024; off <<= 1) {
        const int x = (t >= off) ? sd[t - off] : 0;
        __syncthreads();
        sd[t] += x;
        __syncthreads();
    }
    int base = sd[t] - ssum;
    #pragma unroll
    for (int j = 0; j < 4; ++j) { h[t * 4 + j] = base; base += v[j]; }
}

// 128 blocks x 256 thr. dst = atomicAdd(write-pointer). Within-cell order is
// nondeterministic — exactly as R8-R28 (selection proven order-independent).
__global__ __launch_bounds__(256) void scatter_kernel(
    const float* __restrict__ src_c, const float* __restrict__ tgt_c,
    int* __restrict__ hist, float4* __restrict__ cand)
{
    const int inst = blockIdx.x >> 6;
    const float* __restrict__ coords = inst ? tgt_c : src_c;
    int* __restrict__ h = hist + inst * NCELLS;
    float4* __restrict__ cb = cand + inst * N_PTS;
    const int p = ((blockIdx.x & 63) << 8) + threadIdx.x;
    const float* c = coords + (size_t)p * 3;
    const float x = c[0], y = c[1], z = c[2];
    const int dst = atomicAdd(&h[cell_of(x, y, z)], 1);
    cb[dst] = make_float4(x, y, z, __int_as_float(p));
}

__global__ void aabb_kernel(const float4* __restrict__ cand,
                            float* __restrict__ aabb) {
    const int it = blockIdx.x;                 // inst*NTILES + tile
    const int base = (it / NTILES) * N_PTS + (it % NTILES) * TILE;
    const int lane = threadIdx.x;              // 64 threads, 2 pts each
    float4 a = cand[base + lane], b = cand[base + 64 + lane];
    float mnx = fminf(a.x, b.x), mny = fminf(a.y, b.y), mnz = fminf(a.z, b.z);
    float mxx = fmaxf(a.x, b.x), mxy = fmaxf(a.y, b.y), mxz = fmaxf(a.z, b.z);
    #pragma unroll
    for (int off = 1; off < 64; off <<= 1) {
        mnx = fminf(mnx, __shfl_xor(mnx, off));
        mny = fminf(mny, __shfl_xor(mny, off));
        mnz = fminf(mnz, __shfl_xor(mnz, off));
        mxx = fmaxf(mxx, __shfl_xor(mxx, off));
        mxy = fmaxf(mxy, __shfl_xor(mxy, off));
        mxz = fmaxf(mxz, __shfl_xor(mxz, off));
    }
    if (lane == 0) {
        aabb[it * 6 + 0] = mnx; aabb[it * 6 + 1] = mny; aabb[it * 6 + 2] = mnz;
        aabb[it * 6 + 3] = mxx; aabb[it * 6 + 4] = mxy; aabb[it * 6 + 5] = mxz;
    }
}

// Frozen distance chain for candidate C vs query 0 (do not reorder).
#define DIST_TO0(C, dout)                                                   \
  { const float csq_ = __fmaf_rn((C).z, (C).z, __fmaf_rn((C).y, (C).y,      \
                                 __fmul_rn((C).x, (C).x)));                 \
    float dot_ = __fmul_rn((C).x, qx0);                                     \
    dot_ = __fmaf_rn((C).y, qy0, dot_);                                     \
    dot_ = __fmaf_rn((C).z, qz0, dot_);                                     \
    (dout) = __fmaf_rn(dot_, -2.0f, __fadd_rn(qsq0, csq_)); }

#define LMASK_LT ((1ull << lane) - 1ull)

// Exact 11th-smallest key of 128 wave-held keys (two regs).
#define RADIX11_2(K0, K1, PKOUT)                                            \
  { unsigned pkr_ = 0u;                                                     \
    for (int b_ = 31; b_ >= 0; --b_) {                                      \
      const unsigned mid_ = pkr_ | (1u << b_);                              \
      const int c_ = (int)__popcll(__ballot((K0) < mid_))                   \
                   + (int)__popcll(__ballot((K1) < mid_));                  \
      if (c_ < KK) pkr_ = mid_;                                             \
    }                                                                       \
    (PKOUT) = pkr_; }

// Exact 11th-smallest key of 192 wave-held keys (three regs).
#define RADIX11_3(K0, K1, K2, PKOUT)                                        \
  { unsigned pkr_ = 0u;                                                     \
    for (int b_ = 31; b_ >= 0; --b_) {                                      \
      const unsigned mid_ = pkr_ | (1u << b_);                              \
      const int c_ = (int)__popcll(__ballot((K0) < mid_))                   \
                   + (int)__popcll(__ballot((K1) < mid_))                   \
                   + (int)__popcll(__ballot((K2) < mid_));                  \
      if (c_ < KK) pkr_ = mid_;                                             \
    }                                                                       \
    (PKOUT) = pkr_; }

// Compact the queue to entries <= its exact 11th; W0 becomes the EXACT
// running 11th (queue holds all candidates <= every past W0 >= running
// 11th, so the 11 smallest seen are all present). Wave-local, no atomics.
// Same-wave ds read->write ordering is in-order (proven assumption R10+).
#define COMPACT0                                                            \
  { const int cc_ = cnt0;                                                   \
    const int l1_ = 64 + lane, l2_ = 128 + lane;                            \
    const float cd0_ = (lane < cc_) ? qds[wave][lane] : FLT_MAX;            \
    const int   ci0_ = (lane < cc_) ? qis[wave][lane] : 0x7fffffff;         \
    const float cd1_ = (l1_ < cc_) ? qds[wave][l1_] : FLT_MAX;              \
    const int   ci1_ = (l1_ < cc_) ? qis[wave][l1_] : 0x7fffffff;           \
    const float cd2_ = (l2_ < cc_) ? qds[wave][l2_] : FLT_MAX;              \
    const int   ci2_ = (l2_ < cc_) ? qis[wave][l2_] : 0x7fffffff;           \
    const unsigned ck0_ = keyf(cd0_), ck1_ = keyf(cd1_), ck2_ = keyf(cd2_); \
    unsigned pk_;                                                           \
    RADIX11_3(ck0_, ck1_, ck2_, pk_);                                       \
    W0 = unkeyf(pk_);                                                       \
    const bool f0_ = (ck0_ <= pk_) && (lane < cc_);                         \
    const bool f1_ = (ck1_ <= pk_) && (l1_ < cc_);                          \
    const bool f2_ = (ck2_ <= pk_) && (l2_ < cc_);                          \
    const unsigned long long b0_ = __ballot(f0_), b1_ = __ballot(f1_);      \
    const unsigned long long b2_ = __ballot(f2_);                           \
    const int n0_ = (int)__popcll(b0_), n1_ = (int)__popcll(b1_);           \
    if (f0_) { const int o_ = (int)__popcll(b0_ & LMASK_LT);                \
               qds[wave][o_] = cd0_; qis[wave][o_] = ci0_; }                \
    if (f1_) { const int o_ = n0_ + (int)__popcll(b1_ & LMASK_LT);          \
               qds[wave][o_] = cd1_; qis[wave][o_] = ci1_; }                \
    if (f2_) { const int o_ = n0_ + n1_ + (int)__popcll(b2_ & LMASK_LT);    \
               qds[wave][o_] = cd2_; qis[wave][o_] = ci2_; }                \
    cnt0 = n0_ + n1_ + (int)__popcll(b2_); }

// Gate + capacity-compact + parallel prefix append of a precomputed
// distance D (index CORIG). No per-candidate serial loop.
#define APPEND_D(D, CORIG)                                                  \
  {                                                                         \
    unsigned long long m = __ballot((D) <= W0);                             \
    if (m) {                                                                \
      if (cnt0 + (int)__popcll(m) > QCAP) {                                 \
        COMPACT0;                                                           \
        m = __ballot((D) <= W0);                                            \
      }                                                                     \
      const int base_ = cnt0;                                               \
      const int o_ = base_ + (int)__popcll(m & LMASK_LT);                   \
      if (((m >> lane) & 1ull) && o_ < QCAP) {                              \
        qds[wave][o_] = (D); qis[wave][o_] = (CORIG);                       \
      }                                                                     \
      cnt0 = min(base_ + (int)__popcll(m), QCAP);                           \
    }                                                                       \
  }

// One 64-candidate batch vs the wave's query: dist -> APPEND_D.
#define APPEND_BATCH(C)                                                     \
  {                                                                         \
    float d_;                                                               \
    DIST_TO0((C), d_);                                                      \
    const int corig_ = __float_as_int((C).w);                               \
    APPEND_D(d_, corig_);                                                   \
  }

__global__ __launch_bounds__(NTHREADS) void knn_pool_kernel(
    const float* __restrict__ src_f, const float* __restrict__ tgt_f,
    const float4* __restrict__ cand, const float* __restrict__ aabb,
    float* __restrict__ out)
{
    const int inst = blockIdx.x & 1;
    const float* __restrict__ feats = inst ? tgt_f : src_f;
    float* __restrict__ outb = out + (size_t)inst * N_PTS * (2 * C_FEAT);
    const float4* __restrict__ cd = cand + inst * N_PTS;

    const int tid = threadIdx.x, wave = tid >> 6, lane = tid & 63;

    __shared__ float sab[NTILES * 6];                 // 3 KB
    __shared__ unsigned int slist[NWAVES][NTILES];    // packed (lb|tile), 2 KB
    __shared__ float qds[NWAVES][QCAP];               // 3 KB
    __shared__ int   qis[NWAVES][QCAP];               // 3 KB
    for (int i = tid; i < NTILES * 6; i += NTHREADS)
        sab[i] = aabb[inst * NTILES * 6 + i];
    __syncthreads();

    const int q0 = (blockIdx.x >> 1) * QPB + wave;    // sorted row
    float qx0, qy0, qz0, qsq0;
    int qor0; float W0 = FLT_MAX; int cnt0 = 0;
    {
        const float4 c = cd[q0];
        qx0 = c.x; qy0 = c.y; qz0 = c.z;
        qor0 = __float_as_int(c.w);
        qsq0 = __fmaf_rn(c.z, c.z, __fmaf_rn(c.y, c.y, __fmul_rn(c.x, c.x)));
    }

    const int ownt = q0 / TILE;   // tile containing the query

    // ---- own tile: radix-select exact 11th -> W init + dedup'd append ---
    {
        const float4 c0 = cd[ownt * TILE + lane];
        const float4 c1 = cd[ownt * TILE + 64 + lane];
        float d0, d1;
        DIST_TO0(c0, d0);
        DIST_TO0(c1, d1);
        const unsigned k0 = keyf(d0), k1 = keyf(d1);
        unsigned pk_;
        RADIX11_2(k0, k1, pk_);
        W0 = unkeyf(pk_);
        // Append from the saved distances (no recompute).
        APPEND_D(d0, __float_as_int(c0.w));
        APPEND_D(d1, __float_as_int(c1.w));
    }

    // ---- zigzag (near->far) survivor list: single-query point-to-box lb --
    // keep tile iff lb - eps <= W0 (W0 = exact own-tile 11th; W0 only
    // shrinks -> skip is safe). Entry packs lb: (bits & ~0xFF) | tile —
    // lb>=0 so uint order == lb order; unpacked rounds DOWN => recheck
    // stays conservative.
    int nsurv = 0;
    #pragma unroll
    for (int g = 0; g < 4; ++g) {
        const int p = g * 64 + lane;
        const int o = (p >> 1) + 1;
        const int t = (p & 1) ? (ownt - o) : (ownt + o);
        bool ok = (t >= 0) && (t < NTILES);
        float lb = 0.0f;
        if (ok) {
            const float dx = fmaxf(0.f, fmaxf(sab[t*6+0] - qx0, qx0 - sab[t*6+3]));
            const float dy = fmaxf(0.f, fmaxf(sab[t*6+1] - qy0, qy0 - sab[t*6+4]));
            const float dz = fmaxf(0.f, fmaxf(sab[t*6+2] - qz0, qz0 - sab[t*6+5]));
            lb = dx * dx;
            lb = fmaf(dy, dy, lb);
            lb = fmaf(dz, dz, lb);
            ok = (lb - 1e-3f) <= W0;
        }
        const unsigned long long mk = __ballot(ok);
        if (ok) {
            const int idx = nsurv + (int)__popcll(mk & ((1ull << lane) - 1ull));
            slist[wave][idx] = (__float_as_uint(lb) & 0xFFFFFF00u) | (unsigned)t;
        }
        nsurv += (int)__popcll(mk);
    }

    // ---- scan survivors: 4-slot prefetch ring + LIVE recheck vs W0 ----
    float4 T0a, T0b, T1a, T1b, T2a, T2b, T3a, T3b;
    unsigned int u0 = 0, u1 = 0, u2 = 0, u3 = 0;
    {
        u0 = (0 < nsurv) ? slist[wave][0] : (unsigned)ownt;
        const int t0 = (int)(u0 & 0xFFu);
        T0a = cd[t0 * TILE + lane]; T0b = cd[t0 * TILE + 64 + lane];
        u1 = (1 < nsurv) ? slist[wave][1] : (unsigned)ownt;
        const int t1 = (int)(u1 & 0xFFu);
        T1a = cd[t1 * TILE + lane]; T1b = cd[t1 * TILE + 64 + lane];
        u2 = (2 < nsurv) ? slist[wave][2] : (unsigned)ownt;
        const int t2 = (int)(u2 & 0xFFu);
        T2a = cd[t2 * TILE + lane]; T2b = cd[t2 * TILE + 64 + lane];
        u3 = (3 < nsurv) ? slist[wave][3] : (unsigned)ownt;
        const int t3 = (int)(u3 & 0xFFu);
        T3a = cd[t3 * TILE + lane]; T3b = cd[t3 * TILE + 64 + lane];
    }
    #define SCAN_STEP(UA, TA, TB)                                           \
      {                                                                     \
        const unsigned uN = (s + 4 < nsurv) ? slist[wave][s + 4]            \
                                            : (unsigned)ownt;               \
        const int tn = (int)(uN & 0xFFu);                                   \
        if (__uint_as_float(UA & 0xFFFFFF00u) - 1e-3f <= W0) {              \
            APPEND_BATCH(TA);                                               \
            APPEND_BATCH(TB);                                               \
        }                                                                   \
        UA = uN;                                                            \
        TA = cd[tn * TILE + lane]; TB = cd[tn * TILE + 64 + lane];          \
        ++s;                                                                \
      }
    int s = 0;
    while (s < nsurv) {
        SCAN_STEP(u0, T0a, T0b);
        if (s >= nsurv) break;
        SCAN_STEP(u1, T1a, T1b);
        if (s >= nsurv) break;
        SCAN_STEP(u2, T2a, T2b);
        if (s >= nsurv) break;
        SCAN_STEP(u3, T3a, T3b);
    }
    #undef SCAN_STEP

    // ---- final: exact 11th + compact + bitonic sort + gather ----
    // Sorted ascending lex (d, idx): rank 0 = self/near-twin (dropped
    // positionally, as before); ranks 1..10 -> feature columns 0..9.
    float M0;
    {
        COMPACT0;                         // W0 = exact final 11th; cnt>=11
        const int g_ = cnt0;
        float dl = (lane < g_) ? qds[wave][lane] : FLT_MAX;
        int   il = (lane < g_) ? qis[wave][lane] : 0x7fffffff;
        #pragma unroll
        for (int k = 2; k <= 64; k <<= 1) {
            #pragma unroll
            for (int j = k >> 1; j > 0; j >>= 1) {
                const float pd = __shfl_xor(dl, j);
                const int   pi = __shfl_xor(il, j);
                const bool keepMin = (((lane & k) == 0) == ((lane & j) == 0));
                const bool mineGt = (dl > pd) || (dl == pd && il > pi);
                const bool take = keepMin ? mineGt : !mineGt;
                dl = take ? pd : dl;
                il = take ? pi : il;
            }
        }
        float fv = -FLT_MAX;
        if (lane >= 1 && lane <= KK - 1)
            fv = feats[(size_t)il * C_FEAT + (lane - 1)];
        #pragma unroll
        for (int off = 1; off < 64; off <<= 1)
            fv = fmaxf(fv, __shfl_xor(fv, off));
        M0 = fv;
    }

    {
        const int   row = qor0;
        const float v   = feats[(size_t)row * C_FEAT + lane];
        outb[(size_t)row * (2 * C_FEAT) + lane]          = v;
        outb[(size_t)row * (2 * C_FEAT) + C_FEAT + lane] = M0 - v;
    }
}

extern "C" void kernel_launch(void* const* d_in, const int* in_sizes, int n_in,
                              void* d_out, int out_size, void* d_ws, size_t ws_size,
                              hipStream_t stream) {
    const float* src_f = (const float*)d_in[0];
    const float* tgt_f = (const float*)d_in[1];
    const float* src_c = (const float*)d_in[2];
    const float* tgt_c = (const float*)d_in[3];
    float* out = (float*)d_out;

    char* ws = (char*)d_ws;
    float4* cand = (float4*)(ws + WS_CAND);
    float*  aabb = (float*) (ws + WS_AABB);
    int*    hist = (int*)   (ws + WS_HIST);

    hipMemsetAsync(hist, 0, 2 * NCELLS * sizeof(int), stream);
    hipLaunchKernelGGL(hist_kernel, dim3(128), dim3(256), 0, stream,
                       src_c, tgt_c, hist);
    hipLaunchKernelGGL(scan_kernel, dim3(2), dim3(1024), 0, stream, hist);
    hipLaunchKernelGGL(scatter_kernel, dim3(128), dim3(256), 0, stream,
                       src_c, tgt_c, hist, cand);
    hipLaunchKernelGGL(aabb_kernel, dim3(2 * NTILES), dim3(64), 0, stream,
                       cand, aabb);
    hipLaunchKernelGGL(knn_pool_kernel, dim3(2 * (N_PTS / QPB)), dim3(NTHREADS),
                       0, stream, src_f, tgt_f, cand, aabb, out);
}

// Round 20
// 149.908 us; speedup vs baseline: 1.0319x; 1.0319x over previous
//
#include <hip/hip_runtime.h>
#include <cfloat>
#include <math.h>

// Exact-replication KNN (k=10, +self) + rank-column gather max-pool.
// NUMERICS FROZEN (R3 pass, absmax 0.0): fp32 chains
//   sq  = fma(z,z, fma(y,y, rn(x*x)))
//   dot = fma(z,z', fma(y,y', rn(x*x')))
//   d   = fma(dot, -2, rn(sq_i+sq_j))    [== rn(sum - rn(2*dot)), 2*dot exact]
// Selection order = jax top_k = ascending lexicographic (d, orig_idx) —
// proven order-independent in R8/R9 (absmax 0.0, nondeterministic scatter).
//
// Round 30: revert QCAP to 96 (R29's 192 regressed: 3-reg radix +50%
// ballots/step + wider compact reads + 3KB LDS outweighed the saved
// compactions — compaction count was NOT first-order). Keep R29's free
// win: own-tile dedup (append from saved init distances, bit-identical)
// and the scalarized WQ=1 form. This is R28's proven cost structure +
// a strict instruction reduction.
// Kept: R14 init radix, R16 ring, R22 lb gate, R25 queues, R26 no-pre-gate,
// R27/R28 WQ lever.

#define N_PTS    16384
#define C_FEAT   64
#define KK       11
#define NCELLS   4096                 // 16^3 Morton cells
#define TILE     128                  // sorted points per tile
#define NTILES   (N_PTS / TILE)       // 128
#define WQ       1
#define NWAVES   4
#define NTHREADS (NWAVES * 64)
#define QPB      (NWAVES * WQ)        // 4 queries per block
#define QCAP     96                   // queue slots per query

// d_ws layout (bytes)
#define WS_CAND  0                            // float4[2][N_PTS]   512 KB
#define WS_AABB  (WS_CAND + 2*N_PTS*16)       // float[2][NTILES][6]  6 KB
#define WS_HIST  (WS_AABB + 2*NTILES*6*4)     // int[2][NCELLS]      32 KB

__device__ __forceinline__ int cell_of(float x, float y, float z) {
    int cx = (int)floorf((x + 4.5f) * (16.0f / 9.0f));
    int cy = (int)floorf((y + 4.5f) * (16.0f / 9.0f));
    int cz = (int)floorf((z + 4.5f) * (16.0f / 9.0f));
    cx = min(15, max(0, cx));
    cy = min(15, max(0, cy));
    cz = min(15, max(0, cz));
    int m = 0;
    #pragma unroll
    for (int b = 0; b < 4; ++b)
        m |= (((cx >> b) & 1) << (3 * b)) |
             (((cy >> b) & 1) << (3 * b + 1)) |
             (((cz >> b) & 1) << (3 * b + 2));
    return m;
}

// Monotone (order-preserving, bijective) float<->uint key.
__device__ __forceinline__ unsigned keyf(float f) {
    const unsigned u = __float_as_uint(f);
    return (u & 0x80000000u) ? ~u : (u | 0x80000000u);
}
__device__ __forceinline__ float unkeyf(unsigned k) {
    return __uint_as_float((k & 0x80000000u) ? (k ^ 0x80000000u) : ~k);
}

// 128 blocks x 256 thr, one point per thread. Global atomics into hist
// (pre-zeroed by hipMemsetAsync).
__global__ __launch_bounds__(256) void hist_kernel(
    const float* __restrict__ src_c, const float* __restrict__ tgt_c,
    int* __restrict__ hist)
{
    const int inst = blockIdx.x >> 6;           // 64 blocks per instance
    const float* __restrict__ coords = inst ? tgt_c : src_c;
    int* __restrict__ h = hist + inst * NCELLS;
    const int p = ((blockIdx.x & 63) << 8) + threadIdx.x;
    const float* c = coords + (size_t)p * 3;
    atomicAdd(&h[cell_of(c[0], c[1], c[2])], 1);
}

// One block per instance. Barrier scan; leaves h[cell] = exclusive base.
__global__ __launch_bounds__(1024) void scan_kernel(int* __restrict__ hist)
{
    const int inst = blockIdx.x;
    int* __restrict__ h = hist + inst * NCELLS;
    __shared__ int sd[1024];
    const int t = threadIdx.x;

    int v[4], ssum = 0;
    #pragma unroll
    for (int j = 0; j < 4; ++j) { v[j] = h[t * 4 + j]; ssum += v[j]; }
    sd[t] = ssum;
    __syncthreads();
    for (int off = 1; off < 1024; off <<= 1) {
        const int x = (t >= off) ? sd[t - off] : 0;
        __syncthreads();
        sd[t] += x;
        __syncthreads();
    }
    int base = sd[t] - ssum;
    #pragma unroll
    for (int j = 0; j < 4; ++j) { h[t * 4 + j] = base; base += v[j]; }
}

// 128 blocks x 256 thr. dst = atomicAdd(write-pointer). Within-cell order is
// nondeterministic — exactly as R8-R29 (selection proven order-independent).
__global__ __launch_bounds__(256) void scatter_kernel(
    const float* __restrict__ src_c, const float* __restrict__ tgt_c,
    int* __restrict__ hist, float4* __restrict__ cand)
{
    const int inst = blockIdx.x >> 6;
    const float* __restrict__ coords = inst ? tgt_c : src_c;
    int* __restrict__ h = hist + inst * NCELLS;
    float4* __restrict__ cb = cand + inst * N_PTS;
    const int p = ((blockIdx.x & 63) << 8) + threadIdx.x;
    const float* c = coords + (size_t)p * 3;
    const float x = c[0], y = c[1], z = c[2];
    const int dst = atomicAdd(&h[cell_of(x, y, z)], 1);
    cb[dst] = make_float4(x, y, z, __int_as_float(p));
}

__global__ void aabb_kernel(const float4* __restrict__ cand,
                            float* __restrict__ aabb) {
    const int it = blockIdx.x;                 // inst*NTILES + tile
    const int base = (it / NTILES) * N_PTS + (it % NTILES) * TILE;
    const int lane = threadIdx.x;              // 64 threads, 2 pts each
    float4 a = cand[base + lane], b = cand[base + 64 + lane];
    float mnx = fminf(a.x, b.x), mny = fminf(a.y, b.y), mnz = fminf(a.z, b.z);
    float mxx = fmaxf(a.x, b.x), mxy = fmaxf(a.y, b.y), mxz = fmaxf(a.z, b.z);
    #pragma unroll
    for (int off = 1; off < 64; off <<= 1) {
        mnx = fminf(mnx, __shfl_xor(mnx, off));
        mny = fminf(mny, __shfl_xor(mny, off));
        mnz = fminf(mnz, __shfl_xor(mnz, off));
        mxx = fmaxf(mxx, __shfl_xor(mxx, off));
        mxy = fmaxf(mxy, __shfl_xor(mxy, off));
        mxz = fmaxf(mxz, __shfl_xor(mxz, off));
    }
    if (lane == 0) {
        aabb[it * 6 + 0] = mnx; aabb[it * 6 + 1] = mny; aabb[it * 6 + 2] = mnz;
        aabb[it * 6 + 3] = mxx; aabb[it * 6 + 4] = mxy; aabb[it * 6 + 5] = mxz;
    }
}

// Frozen distance chain for candidate C vs query 0 (do not reorder).
#define DIST_TO0(C, dout)                                                   \
  { const float csq_ = __fmaf_rn((C).z, (C).z, __fmaf_rn((C).y, (C).y,      \
                                 __fmul_rn((C).x, (C).x)));                 \
    float dot_ = __fmul_rn((C).x, qx0);                                     \
    dot_ = __fmaf_rn((C).y, qy0, dot_);                                     \
    dot_ = __fmaf_rn((C).z, qz0, dot_);                                     \
    (dout) = __fmaf_rn(dot_, -2.0f, __fadd_rn(qsq0, csq_)); }

#define LMASK_LT ((1ull << lane) - 1ull)

// Exact 11th-smallest key of 128 wave-held keys (two regs).
#define RADIX11_2(K0, K1, PKOUT)                                            \
  { unsigned pkr_ = 0u;                                                     \
    for (int b_ = 31; b_ >= 0; --b_) {                                      \
      const unsigned mid_ = pkr_ | (1u << b_);                              \
      const int c_ = (int)__popcll(__ballot((K0) < mid_))                   \
                   + (int)__popcll(__ballot((K1) < mid_));                  \
      if (c_ < KK) pkr_ = mid_;                                             \
    }                                                                       \
    (PKOUT) = pkr_; }

// Compact the queue to entries <= its exact 11th; W0 becomes the EXACT
// running 11th (queue holds all candidates <= every past W0 >= running
// 11th, so the 11 smallest seen are all present). Wave-local, no atomics.
// Same-wave ds read->write ordering is in-order (proven assumption R10+).
#define COMPACT0                                                            \
  { const int cc_ = cnt0;                                                   \
    const int l1_ = 64 + lane;                                              \
    const float cd0_ = (lane < cc_) ? qds[wave][lane] : FLT_MAX;            \
    const int   ci0_ = (lane < cc_) ? qis[wave][lane] : 0x7fffffff;         \
    const float cd1_ = (l1_ < cc_) ? qds[wave][l1_] : FLT_MAX;              \
    const int   ci1_ = (l1_ < cc_) ? qis[wave][l1_] : 0x7fffffff;           \
    const unsigned ck0_ = keyf(cd0_), ck1_ = keyf(cd1_);                    \
    unsigned pk_;                                                           \
    RADIX11_2(ck0_, ck1_, pk_);                                             \
    W0 = unkeyf(pk_);                                                       \
    const bool f0_ = (ck0_ <= pk_) && (lane < cc_);                         \
    const bool f1_ = (ck1_ <= pk_) && (l1_ < cc_);                          \
    const unsigned long long b0_ = __ballot(f0_), b1_ = __ballot(f1_);      \
    const int n0_ = (int)__popcll(b0_);                                     \
    if (f0_) { const int o_ = (int)__popcll(b0_ & LMASK_LT);                \
               qds[wave][o_] = cd0_; qis[wave][o_] = ci0_; }                \
    if (f1_) { const int o_ = n0_ + (int)__popcll(b1_ & LMASK_LT);          \
               qds[wave][o_] = cd1_; qis[wave][o_] = ci1_; }                \
    cnt0 = n0_ + (int)__popcll(b1_); }

// Gate + capacity-compact + parallel prefix append of a precomputed
// distance D (index CORIG). No per-candidate serial loop.
#define APPEND_D(D, CORIG)                                                  \
  {                                                                         \
    unsigned long long m = __ballot((D) <= W0);                             \
    if (m) {                                                                \
      if (cnt0 + (int)__popcll(m) > QCAP) {                                 \
        COMPACT0;                                                           \
        m = __ballot((D) <= W0);                                            \
      }                                                                     \
      const int base_ = cnt0;                                               \
      const int o_ = base_ + (int)__popcll(m & LMASK_LT);                   \
      if (((m >> lane) & 1ull) && o_ < QCAP) {                              \
        qds[wave][o_] = (D); qis[wave][o_] = (CORIG);                       \
      }                                                                     \
      cnt0 = min(base_ + (int)__popcll(m), QCAP);                           \
    }                                                                       \
  }

// One 64-candidate batch vs the wave's query: dist -> APPEND_D.
#define APPEND_BATCH(C)                                                     \
  {                                                                         \
    float d_;                                                               \
    DIST_TO0((C), d_);                                                      \
    const int corig_ = __float_as_int((C).w);                               \
    APPEND_D(d_, corig_);                                                   \
  }

__global__ __launch_bounds__(NTHREADS) void knn_pool_kernel(
    const float* __restrict__ src_f, const float* __restrict__ tgt_f,
    const float4* __restrict__ cand, const float* __restrict__ aabb,
    float* __restrict__ out)
{
    const int inst = blockIdx.x & 1;
    const float* __restrict__ feats = inst ? tgt_f : src_f;
    float* __restrict__ outb = out + (size_t)inst * N_PTS * (2 * C_FEAT);
    const float4* __restrict__ cd = cand + inst * N_PTS;

    const int tid = threadIdx.x, wave = tid >> 6, lane = tid & 63;

    __shared__ float sab[NTILES * 6];                 // 3 KB
    __shared__ unsigned int slist[NWAVES][NTILES];    // packed (lb|tile), 2 KB
    __shared__ float qds[NWAVES][QCAP];               // 1.5 KB
    __shared__ int   qis[NWAVES][QCAP];               // 1.5 KB
    for (int i = tid; i < NTILES * 6; i += NTHREADS)
        sab[i] = aabb[inst * NTILES * 6 + i];
    __syncthreads();

    const int q0 = (blockIdx.x >> 1) * QPB + wave;    // sorted row
    float qx0, qy0, qz0, qsq0;
    int qor0; float W0 = FLT_MAX; int cnt0 = 0;
    {
        const float4 c = cd[q0];
        qx0 = c.x; qy0 = c.y; qz0 = c.z;
        qor0 = __float_as_int(c.w);
        qsq0 = __fmaf_rn(c.z, c.z, __fmaf_rn(c.y, c.y, __fmul_rn(c.x, c.x)));
    }

    const int ownt = q0 / TILE;   // tile containing the query

    // ---- own tile: radix-select exact 11th -> W init + dedup'd append ---
    {
        const float4 c0 = cd[ownt * TILE + lane];
        const float4 c1 = cd[ownt * TILE + 64 + lane];
        float d0, d1;
        DIST_TO0(c0, d0);
        DIST_TO0(c1, d1);
        const unsigned k0 = keyf(d0), k1 = keyf(d1);
        unsigned pk_;
        RADIX11_2(k0, k1, pk_);
        W0 = unkeyf(pk_);
        // Append from the saved distances (no recompute).
        APPEND_D(d0, __float_as_int(c0.w));
        APPEND_D(d1, __float_as_int(c1.w));
    }

    // ---- zigzag (near->far) survivor list: single-query point-to-box lb --
    // keep tile iff lb - eps <= W0 (W0 = exact own-tile 11th; W0 only
    // shrinks -> skip is safe). Entry packs lb: (bits & ~0xFF) | tile —
    // lb>=0 so uint order == lb order; unpacked rounds DOWN => recheck
    // stays conservative.
    int nsurv = 0;
    #pragma unroll
    for (int g = 0; g < 4; ++g) {
        const int p = g * 64 + lane;
        const int o = (p >> 1) + 1;
        const int t = (p & 1) ? (ownt - o) : (ownt + o);
        bool ok = (t >= 0) && (t < NTILES);
        float lb = 0.0f;
        if (ok) {
            const float dx = fmaxf(0.f, fmaxf(sab[t*6+0] - qx0, qx0 - sab[t*6+3]));
            const float dy = fmaxf(0.f, fmaxf(sab[t*6+1] - qy0, qy0 - sab[t*6+4]));
            const float dz = fmaxf(0.f, fmaxf(sab[t*6+2] - qz0, qz0 - sab[t*6+5]));
            lb = dx * dx;
            lb = fmaf(dy, dy, lb);
            lb = fmaf(dz, dz, lb);
            ok = (lb - 1e-3f) <= W0;
        }
        const unsigned long long mk = __ballot(ok);
        if (ok) {
            const int idx = nsurv + (int)__popcll(mk & ((1ull << lane) - 1ull));
            slist[wave][idx] = (__float_as_uint(lb) & 0xFFFFFF00u) | (unsigned)t;
        }
        nsurv += (int)__popcll(mk);
    }

    // ---- scan survivors: 4-slot prefetch ring + LIVE recheck vs W0 ----
    float4 T0a, T0b, T1a, T1b, T2a, T2b, T3a, T3b;
    unsigned int u0 = 0, u1 = 0, u2 = 0, u3 = 0;
    {
        u0 = (0 < nsurv) ? slist[wave][0] : (unsigned)ownt;
        const int t0 = (int)(u0 & 0xFFu);
        T0a = cd[t0 * TILE + lane]; T0b = cd[t0 * TILE + 64 + lane];
        u1 = (1 < nsurv) ? slist[wave][1] : (unsigned)ownt;
        const int t1 = (int)(u1 & 0xFFu);
        T1a = cd[t1 * TILE + lane]; T1b = cd[t1 * TILE + 64 + lane];
        u2 = (2 < nsurv) ? slist[wave][2] : (unsigned)ownt;
        const int t2 = (int)(u2 & 0xFFu);
        T2a = cd[t2 * TILE + lane]; T2b = cd[t2 * TILE + 64 + lane];
        u3 = (3 < nsurv) ? slist[wave][3] : (unsigned)ownt;
        const int t3 = (int)(u3 & 0xFFu);
        T3a = cd[t3 * TILE + lane]; T3b = cd[t3 * TILE + 64 + lane];
    }
    #define SCAN_STEP(UA, TA, TB)                                           \
      {                                                                     \
        const unsigned uN = (s + 4 < nsurv) ? slist[wave][s + 4]            \
                                            : (unsigned)ownt;               \
        const int tn = (int)(uN & 0xFFu);                                   \
        if (__uint_as_float(UA & 0xFFFFFF00u) - 1e-3f <= W0) {              \
            APPEND_BATCH(TA);                                               \
            APPEND_BATCH(TB);                                               \
        }                                                                   \
        UA = uN;                                                            \
        TA = cd[tn * TILE + lane]; TB = cd[tn * TILE + 64 + lane];          \
        ++s;                                                                \
      }
    int s = 0;
    while (s < nsurv) {
        SCAN_STEP(u0, T0a, T0b);
        if (s >= nsurv) break;
        SCAN_STEP(u1, T1a, T1b);
        if (s >= nsurv) break;
        SCAN_STEP(u2, T2a, T2b);
        if (s >= nsurv) break;
        SCAN_STEP(u3, T3a, T3b);
    }
    #undef SCAN_STEP

    // ---- final: exact 11th + compact + bitonic sort + gather ----
    // Sorted ascending lex (d, idx): rank 0 = self/near-twin (dropped
    // positionally, as before); ranks 1..10 -> feature columns 0..9.
    float M0;
    {
        COMPACT0;                         // W0 = exact final 11th; cnt>=11
        const int g_ = cnt0;
        float dl = (lane < g_) ? qds[wave][lane] : FLT_MAX;
        int   il = (lane < g_) ? qis[wave][lane] : 0x7fffffff;
        #pragma unroll
        for (int k = 2; k <= 64; k <<= 1) {
            #pragma unroll
            for (int j = k >> 1; j > 0; j >>= 1) {
                const float pd = __shfl_xor(dl, j);
                const int   pi = __shfl_xor(il, j);
                const bool keepMin = (((lane & k) == 0) == ((lane & j) == 0));
                const bool mineGt = (dl > pd) || (dl == pd && il > pi);
                const bool take = keepMin ? mineGt : !mineGt;
                dl = take ? pd : dl;
                il = take ? pi : il;
            }
        }
        float fv = -FLT_MAX;
        if (lane >= 1 && lane <= KK - 1)
            fv = feats[(size_t)il * C_FEAT + (lane - 1)];
        #pragma unroll
        for (int off = 1; off < 64; off <<= 1)
            fv = fmaxf(fv, __shfl_xor(fv, off));
        M0 = fv;
    }

    {
        const int   row = qor0;
        const float v   = feats[(size_t)row * C_FEAT + lane];
        outb[(size_t)row * (2 * C_FEAT) + lane]          = v;
        outb[(size_t)row * (2 * C_FEAT) + C_FEAT + lane] = M0 - v;
    }
}

extern "C" void kernel_launch(void* const* d_in, const int* in_sizes, int n_in,
                              void* d_out, int out_size, void* d_ws, size_t ws_size,
                              hipStream_t stream) {
    const float* src_f = (const float*)d_in[0];
    const float* tgt_f = (const float*)d_in[1];
    const float* src_c = (const float*)d_in[2];
    const float* tgt_c = (const float*)d_in[3];
    float* out = (float*)d_out;

    char* ws = (char*)d_ws;
    float4* cand = (float4*)(ws + WS_CAND);
    float*  aabb = (float*) (ws + WS_AABB);
    int*    hist = (int*)   (ws + WS_HIST);

    hipMemsetAsync(hist, 0, 2 * NCELLS * sizeof(int), stream);
    hipLaunchKernelGGL(hist_kernel, dim3(128), dim3(256), 0, stream,
                       src_c, tgt_c, hist);
    hipLaunchKernelGGL(scan_kernel, dim3(2), dim3(1024), 0, stream, hist);
    hipLaunchKernelGGL(scatter_kernel, dim3(128), dim3(256), 0, stream,
                       src_c, tgt_c, hist, cand);
    hipLaunchKernelGGL(aabb_kernel, dim3(2 * NTILES), dim3(64), 0, stream,
                       cand, aabb);
    hipLaunchKernelGGL(knn_pool_kernel, dim3(2 * (N_PTS / QPB)), dim3(NTHREADS),
                       0, stream, src_f, tgt_f, cand, aabb, out);
}